// Round 11
// baseline (115.375 us; speedup 1.0000x reference)
//
#include <hip/hip_runtime.h>
#include <hip/hip_bf16.h>
#include <math.h>

// NUM_MAPS=512, ZG=512, HID=96, SEQ=8, H1=3, H2=16, NPROC=8. fp32 in/out.
// R10: XCD swizzle (proc = blk%8) verified, 107.9us. R11: merge kB+kC into
// one kernel kBC (64 blocks): each block redundantly computes attn1, fc1,
// Qq, K2/V2 (no cross-block deps -> no grid sync needed), then its 64-map
// Wo slice + epilogue. 8 same-proc blocks/XCD share fc1/Wk2/Wv2/fc2/Wq2
// lines via L2 (R10). fc1+Wk2+Wv2 (108KB) burst-staged to dynamic LDS
// (136KB total; R8 proved >64KB dynamic works). fc2/Wq2/Wo read in-phase:
// compile-time addresses -> compiler hoists loads to entry (R7 lesson).
// Saves one launch gap + ramp (~3-4us) for ~1.5-2us redundant work.

#define WS_ALPHA 0
#define WS_Q     512
#define WS_QKV   608      // 8*2304 -> 19040

// kBC dynamic-LDS layout (float offsets)
#define SQK 0
#define SKK 768
#define SVV 1536
#define SH  2304
#define SH2 3072
#define SK2 3840
#define SV2 4608
#define SQ  5376
#define SQQ 5472
#define SO  5568
#define SOF 5664
#define SE2 5760
#define SG  5888
#define SS  5896
#define SP  6088
#define WF1 6344          // fc1 9216
#define WK2 15560         // Wk2 9216
#define WV2 24776         // Wv2 9216
#define LDS_FLOATS 33992  // 135968 B

// ---------------------------------------------------------------------------
// KA (182 x 256): unchanged from R10 (verified).
//  blk 0..143   : QKV1. proc = blk%8 (XCD), rem = blk/8 -> (mat, six).
//  blk 144..175 : alpha. 16 m/blk, 16-way k-split, W hoisted.
//  blk 176..181 : q. 16 h/blk, 16-way k-split, W hoisted.
// ---------------------------------------------------------------------------
__global__ __launch_bounds__(256) void kA_qkv_alpha_q(
    const float* __restrict__ x, const float* __restrict__ Wa,
    const float* __restrict__ ba, const float* __restrict__ Wqr,
    const float* __restrict__ bqr, const float* __restrict__ P,
    const float* __restrict__ Wq1, const float* __restrict__ Wk1,
    const float* __restrict__ Wv1, float* __restrict__ ws)
{
    __shared__ float sK[8 * 528];   // skewed K tile (c -> c + c/32), or x
    __shared__ float sp[2048];      // partial sums
    const int blk = blockIdx.x, tid = threadIdx.x;

    if (blk < 144) {
        const int proc = blk & 7, rem = blk >> 3;       // proc -> XCD
        const int mat = rem / 6, six = rem % 6;
        const int hl = tid & 15, ks = tid >> 4;        // ks 0..15
        const int h = six * 16 + hl;
        const float* W = (mat == 0 ? Wq1 : (mat == 1 ? Wk1 : Wv1))
                         + proc * 49152 + (ks * 32) * 96 + h;
        float wreg[32];
        #pragma unroll
        for (int m2 = 0; m2 < 32; ++m2) wreg[m2] = W[m2 * 96];  // issued early
        const float4* P4 = (const float4*)(P + proc * 4096);
        for (int i = tid; i < 1024; i += 256) {
            float4 v = P4[i];
            const int c = i >> 1, off = (i & 1) * 4;
            const int cp = c + (c >> 5);
            sK[(off + 0) * 528 + cp] = v.x;
            sK[(off + 1) * 528 + cp] = v.y;
            sK[(off + 2) * 528 + cp] = v.z;
            sK[(off + 3) * 528 + cp] = v.w;
        }
        __syncthreads();
        const float* Kb = sK + ks * 33;                // skewed base
        float acc[8] = {0.f,0.f,0.f,0.f,0.f,0.f,0.f,0.f};
        #pragma unroll
        for (int m2 = 0; m2 < 32; ++m2) {
            const float w = wreg[m2];
            const float* Kc = Kb + m2;
            #pragma unroll
            for (int s = 0; s < 8; ++s) acc[s] += Kc[s * 528] * w;
        }
        float* spb = sp + ks * 128 + hl * 8;
        #pragma unroll
        for (int s = 0; s < 8; ++s) spb[s] = acc[s];
        __syncthreads();
        if (tid < 128) {            // tid = hl2*8 + s
            float a = 0.f;
            #pragma unroll
            for (int u = 0; u < 16; ++u) a += sp[u * 128 + tid];
            const int hl2 = tid >> 3, s = tid & 7;
            ws[WS_QKV + proc * 2304 + mat * 768 + s * 96 + six * 16 + hl2] = a;
        }
    } else if (blk < 176) {
        const int ml = tid & 15, ks = tid >> 4;        // 32 k each
        const int m = (blk - 144) * 16 + ml;
        const float* W = Wa + (ks * 32) * 512 + m;
        float wreg[32];
        #pragma unroll
        for (int k = 0; k < 32; ++k) wreg[k] = W[k * 512];
        for (int k = tid; k < 512; k += 256) sK[k] = x[k];
        __syncthreads();
        const float* xq = sK + ks * 32;
        float acc = 0.f;
        #pragma unroll
        for (int k = 0; k < 32; ++k) acc += xq[k] * wreg[k];
        sp[tid] = acc;
        __syncthreads();
        if (tid < 16) {
            float a = ba[(blk - 144) * 16 + tid];
            #pragma unroll
            for (int u = 0; u < 16; ++u) a += sp[u * 16 + tid];
            ws[WS_ALPHA + (blk - 144) * 16 + tid] = 1.f / (1.f + __expf(-a));
        }
    } else {
        const int hl = tid & 15, ks = tid >> 4;        // 32 k each
        const int h = (blk - 176) * 16 + hl;           // 6*16 = 96
        const float* W = Wqr + (ks * 32) * 96 + h;
        float wreg[32];
        #pragma unroll
        for (int k = 0; k < 32; ++k) wreg[k] = W[k * 96];
        for (int k = tid; k < 512; k += 256) sK[k] = x[k];
        __syncthreads();
        const float* xq = sK + ks * 32;
        float acc = 0.f;
        #pragma unroll
        for (int k = 0; k < 32; ++k) acc += xq[k] * wreg[k];
        sp[tid] = acc;
        __syncthreads();
        if (tid < 16) {
            float a = bqr[(blk - 176) * 16 + tid];
            #pragma unroll
            for (int u = 0; u < 16; ++u) a += sp[u * 16 + tid];
            ws[WS_Q + (blk - 176) * 16 + tid] = fmaxf(a, 0.f);
        }
    }
}

// ---------------------------------------------------------------------------
// KBC (64 x 256, 136KB dynamic LDS): proc = blk%8 (XCD), e = blk/8.
// Entry: burst-stage fc1/Wk2/Wv2 (108KB) to LDS; QKV1/q from ws; epilogue
// operands to regs. Then attn1 -> fc1 (+Qq global) -> K2/V2 -> attn2 ->
// fc2 (global col-wise) -> Wo slice (global) + epilogue. No cross-block dep.
// ---------------------------------------------------------------------------
__global__ __launch_bounds__(256) void kBC_all(
    const float* __restrict__ gate, const float* __restrict__ De,
    const float* __restrict__ regs, const float* __restrict__ fc1w,
    const float* __restrict__ Wq2,  const float* __restrict__ Wk2,
    const float* __restrict__ Wv2,  const float* __restrict__ fc2w,
    const float* __restrict__ Wo,   const float* __restrict__ ws,
    float* __restrict__ out)
{
    extern __shared__ float sm[];
    const int b = blockIdx.x, proc = b & 7, e = b >> 3, tid = threadIdx.x;
    const float rs = 0.10206207261596577f;  // 1/sqrt(96)

    // ---- entry burst: fc1, Wk2, Wv2 -> LDS (coalesced float4, once) ----
    {
        const float4* F1 = (const float4*)fc1w + proc * 2304;
        const float4* K4 = (const float4*)Wk2 + proc * 2304;
        const float4* V4 = (const float4*)Wv2 + proc * 2304;
        float4* d1 = (float4*)(sm + WF1);
        float4* d2 = (float4*)(sm + WK2);
        float4* d3 = (float4*)(sm + WV2);
        #pragma unroll
        for (int r = 0; r < 9; ++r) {
            const int i = tid + 256 * r;
            d1[i] = F1[i]; d2[i] = K4[i]; d3[i] = V4[i];
        }
    }
    const float* qkv = ws + WS_QKV + proc * 2304;
    for (int i = tid; i < 768; i += 256) {
        sm[SQK + i] = qkv[i];
        sm[SKK + i] = qkv[768 + i];
        sm[SVV + i] = qkv[1536 + i];
    }
    if (tid < 96) sm[SQ + tid] = ws[WS_Q + tid];
    else if (tid < 104) sm[SG + tid - 96] = gate[tid - 96];
    // epilogue operands -> regs (per ml; duplicated across ks, cheap)
    const int ml = tid & 63, ks = tid >> 6;
    const int m = 64 * e + ml;
    const float4* Dp4 = (const float4*)(De + proc * 4096 + m * 8);
    const float4 d0 = Dp4[0], d1v = Dp4[1];
    const float av = ws[WS_ALPHA + m];
    const float rg = regs[proc * 512 + m];
    __syncthreads();

    // attn1 logits (h0, si, sk)
    if (tid < 192) {
        const int h0 = tid / 64, r64 = tid % 64, si = r64 / 8, sk = r64 % 8;
        float acc = 0.f;
        #pragma unroll
        for (int d = 0; d < 32; ++d)
            acc += sm[SQK + si * 96 + h0 * 32 + d] * sm[SKK + sk * 96 + h0 * 32 + d];
        sm[SS + tid] = acc * rs;
    }
    __syncthreads();
    if (tid < 24) {        // softmax row -> probs in place
        float* row = sm + SS + tid * 8;
        float mx = row[0];
        #pragma unroll
        for (int k = 1; k < 8; ++k) mx = fmaxf(mx, row[k]);
        float ex[8], sum = 0.f;
        #pragma unroll
        for (int k = 0; k < 8; ++k) { ex[k] = __expf(row[k] - mx); sum += ex[k]; }
        const float inv = 1.f / sum;
        #pragma unroll
        for (int k = 0; k < 8; ++k) row[k] = ex[k] * inv;
    }
    __syncthreads();
    if (tid < 192) {       // AV + residual (h0, si, dq): 4 d's each
        const int h0 = tid / 64, r64 = tid % 64, si = r64 / 8, dq = r64 % 8;
        const float* ep = sm + SS + h0 * 64 + si * 8;
        float o0 = 0.f, o1 = 0.f, o2 = 0.f, o3 = 0.f;
        #pragma unroll
        for (int k = 0; k < 8; ++k) {
            const float ek = ep[k];
            const float* v = sm + SVV + k * 96 + h0 * 32 + dq * 4;
            o0 += ek*v[0]; o1 += ek*v[1]; o2 += ek*v[2]; o3 += ek*v[3];
        }
        const int base = si * 96 + h0 * 32 + dq * 4;
        sm[SH+base+0] = sm[SQK+base+0] + o0;  sm[SH+base+1] = sm[SQK+base+1] + o1;
        sm[SH+base+2] = sm[SQK+base+2] + o2;  sm[SH+base+3] = sm[SQK+base+3] + o3;
    }
    __syncthreads();
    // fc1 from LDS: 3 outputs/thread; Qq from global (tid<96, coalesced)
    #pragma unroll
    for (int r = 0; r < 3; ++r) {
        const int idx = tid + 256 * r, s = idx / 96, j = idx % 96;
        const float* Hs = sm + SH + s * 96;
        float acc = 0.f;
        #pragma unroll
        for (int i = 0; i < 96; ++i) acc += Hs[i] * sm[WF1 + i * 96 + j];
        sm[SH2 + idx] = sm[SH + idx] + fmaxf(acc, 0.f);
    }
    if (tid < 96) {
        const float* W = Wq2 + proc * 9216 + tid;
        float acc = 0.f;
        #pragma unroll
        for (int i = 0; i < 96; ++i) acc += sm[SQ + i] * W[i * 96];
        sm[SQQ + tid] = acc;
    }
    __syncthreads();
    // K2/V2 from LDS: 6 outputs/thread
    #pragma unroll
    for (int r = 0; r < 6; ++r) {
        const int idx = tid + 256 * r;          // 0..1535
        const int mat = idx / 768, rr = idx % 768, s = rr / 96, j = rr % 96;
        const float* Hs = sm + SH2 + s * 96;
        const float* Wt = sm + (mat ? WV2 : WK2) + j;
        float acc = 0.f;
        #pragma unroll
        for (int i = 0; i < 96; ++i) acc += Hs[i] * Wt[i * 96];
        sm[(mat ? SV2 : SK2) + rr] = acc;
    }
    __syncthreads();
    // attn2 probs: 16 heads, d=6, 1 query row
    if (tid < 16) {
        const int h0 = tid;
        float lg[8], mx = -1e30f;
        #pragma unroll
        for (int k = 0; k < 8; ++k) {
            float acc = 0.f;
            #pragma unroll
            for (int d = 0; d < 6; ++d)
                acc += sm[SQQ + h0 * 6 + d] * sm[SK2 + k * 96 + h0 * 6 + d];
            lg[k] = acc * rs; mx = fmaxf(mx, lg[k]);
        }
        float ex[8], sum = 0.f;
        #pragma unroll
        for (int k = 0; k < 8; ++k) { ex[k] = __expf(lg[k] - mx); sum += ex[k]; }
        const float inv = 1.f / sum;
        #pragma unroll
        for (int k = 0; k < 8; ++k) sm[SE2 + h0 * 8 + k] = ex[k] * inv;
    }
    __syncthreads();
    if (tid < 96) {        // AV + residual
        const int h0 = tid / 6;
        float o = 0.f;
        #pragma unroll
        for (int k = 0; k < 8; ++k)
            o += sm[SE2 + h0 * 8 + k] * sm[SV2 + k * 96 + tid];
        sm[SO + tid] = sm[SQQ + tid] + o;
    }
    __syncthreads();
    if (tid < 96) {        // fc2 from global, col-wise (coalesced per i)
        const float* W = fc2w + proc * 9216 + tid;
        float acc = 0.f;
        #pragma unroll
        for (int i = 0; i < 96; ++i) acc += sm[SO + i] * W[i * 96];
        sm[SOF + tid] = sm[SO + tid] + fmaxf(acc, 0.f);
    }
    __syncthreads();
    // Wo slice from global (lanes 0..63 contiguous m), 4-way k-split
    {
        const float* W = Wo + proc * 49152 + m;
        float acc = 0.f;
        #pragma unroll
        for (int i = 0; i < 24; ++i)
            acc += sm[SOF + 24 * ks + i] * W[(24 * ks + i) * 512];
        sm[SP + tid] = acc;
    }
    __syncthreads();
    if (ks == 0) {
        const float tr = sm[SP + ml] + sm[SP + ml + 64]
                       + sm[SP + ml + 128] + sm[SP + ml + 192];
        const float de = d0.x * sm[SG+0] + d0.y * sm[SG+1]
                       + d0.z * sm[SG+2] + d0.w * sm[SG+3]
                       + d1v.x * sm[SG+4] + d1v.y * sm[SG+5]
                       + d1v.z * sm[SG+6] + d1v.w * sm[SG+7];
        const float mix = av * tr + (1.f - av) * de;
        const int pt = proc & 3;                 // gamma gets +1, beta not
        const float off = (pt == 0 || pt == 2) ? 1.f : 0.f;
        out[proc * 512 + m] = mix * rg + off;
    }
}

extern "C" void kernel_launch(void* const* d_in, const int* in_sizes, int n_in,
                              void* d_out, int out_size, void* d_ws, size_t ws_size,
                              hipStream_t stream)
{
    const float* gate = (const float*)d_in[0];
    const float* x    = (const float*)d_in[1];
    const float* Wa   = (const float*)d_in[2];
    const float* ba   = (const float*)d_in[3];
    const float* Wqr  = (const float*)d_in[4];
    const float* bqr  = (const float*)d_in[5];
    const float* P    = (const float*)d_in[6];
    const float* De   = (const float*)d_in[7];
    const float* regs = (const float*)d_in[8];
    const float* Wq1  = (const float*)d_in[9];
    const float* Wk1  = (const float*)d_in[10];
    const float* Wv1  = (const float*)d_in[11];
    const float* fc1  = (const float*)d_in[12];
    const float* Wq2  = (const float*)d_in[13];
    const float* Wk2  = (const float*)d_in[14];
    const float* Wv2  = (const float*)d_in[15];
    const float* fc2  = (const float*)d_in[16];
    const float* Wo   = (const float*)d_in[17];
    float* ws = (float*)d_ws;

    hipLaunchKernelGGL(kA_qkv_alpha_q, dim3(182), dim3(256), 0, stream,
                       x, Wa, ba, Wqr, bqr, P, Wq1, Wk1, Wv1, ws);
    hipLaunchKernelGGL(kBC_all, dim3(64), dim3(256),
                       LDS_FLOATS * sizeof(float), stream,
                       gate, De, regs, fc1, Wq2, Wk2, Wv2, fc2, Wo,
                       ws, (float*)d_out);
}

// Round 12
// 110.451 us; speedup vs baseline: 1.0446x; 1.0446x over previous
//
#include <hip/hip_runtime.h>
#include <hip/hip_bf16.h>
#include <math.h>

// NUM_MAPS=512, ZG=512, HID=96, SEQ=8, H1=3, H2=16, NPROC=8. fp32 in/out.
// R11 post-mortem: kBC with 136KB DYNAMIC LDS ran 54.5us despite ~5us of
// work (VALUBusy 1.3%, FETCH 1.85MB = unique footprint -> L2 sharing fine).
// R8's 88.8KB-dynamic-LDS kernel also sat at ~54us with a different body:
// the common factor is dynamic LDS > 64KB/workgroup => ~50us dispatch tax
// (NOT the spin barrier as R8 concluded). Rule: stay <= 64KB static.
// R12: same kB+kC merge, but static 25KB LDS (activations only); weights
// read from global with full unrolls (compiler hoists; XCD/L2 8-way share
// verified by R10/R11 FETCH).

#define WS_ALPHA 0
#define WS_Q     512
#define WS_QKV   608      // 8*2304 -> 19040

// ---------------------------------------------------------------------------
// KA (182 x 256): unchanged from R10 (verified).
//  blk 0..143   : QKV1. proc = blk%8 (XCD), rem = blk/8 -> (mat, six).
//  blk 144..175 : alpha. 16 m/blk, 16-way k-split, W hoisted.
//  blk 176..181 : q. 16 h/blk, 16-way k-split, W hoisted.
// ---------------------------------------------------------------------------
__global__ __launch_bounds__(256) void kA_qkv_alpha_q(
    const float* __restrict__ x, const float* __restrict__ Wa,
    const float* __restrict__ ba, const float* __restrict__ Wqr,
    const float* __restrict__ bqr, const float* __restrict__ P,
    const float* __restrict__ Wq1, const float* __restrict__ Wk1,
    const float* __restrict__ Wv1, float* __restrict__ ws)
{
    __shared__ float sK[8 * 528];   // skewed K tile (c -> c + c/32), or x
    __shared__ float sp[2048];      // partial sums
    const int blk = blockIdx.x, tid = threadIdx.x;

    if (blk < 144) {
        const int proc = blk & 7, rem = blk >> 3;       // proc -> XCD
        const int mat = rem / 6, six = rem % 6;
        const int hl = tid & 15, ks = tid >> 4;        // ks 0..15
        const int h = six * 16 + hl;
        const float* W = (mat == 0 ? Wq1 : (mat == 1 ? Wk1 : Wv1))
                         + proc * 49152 + (ks * 32) * 96 + h;
        float wreg[32];
        #pragma unroll
        for (int m2 = 0; m2 < 32; ++m2) wreg[m2] = W[m2 * 96];  // issued early
        const float4* P4 = (const float4*)(P + proc * 4096);
        for (int i = tid; i < 1024; i += 256) {
            float4 v = P4[i];
            const int c = i >> 1, off = (i & 1) * 4;
            const int cp = c + (c >> 5);
            sK[(off + 0) * 528 + cp] = v.x;
            sK[(off + 1) * 528 + cp] = v.y;
            sK[(off + 2) * 528 + cp] = v.z;
            sK[(off + 3) * 528 + cp] = v.w;
        }
        __syncthreads();
        const float* Kb = sK + ks * 33;                // skewed base
        float acc[8] = {0.f,0.f,0.f,0.f,0.f,0.f,0.f,0.f};
        #pragma unroll
        for (int m2 = 0; m2 < 32; ++m2) {
            const float w = wreg[m2];
            const float* Kc = Kb + m2;
            #pragma unroll
            for (int s = 0; s < 8; ++s) acc[s] += Kc[s * 528] * w;
        }
        float* spb = sp + ks * 128 + hl * 8;
        #pragma unroll
        for (int s = 0; s < 8; ++s) spb[s] = acc[s];
        __syncthreads();
        if (tid < 128) {            // tid = hl2*8 + s
            float a = 0.f;
            #pragma unroll
            for (int u = 0; u < 16; ++u) a += sp[u * 128 + tid];
            const int hl2 = tid >> 3, s = tid & 7;
            ws[WS_QKV + proc * 2304 + mat * 768 + s * 96 + six * 16 + hl2] = a;
        }
    } else if (blk < 176) {
        const int ml = tid & 15, ks = tid >> 4;        // 32 k each
        const int m = (blk - 144) * 16 + ml;
        const float* W = Wa + (ks * 32) * 512 + m;
        float wreg[32];
        #pragma unroll
        for (int k = 0; k < 32; ++k) wreg[k] = W[k * 512];
        for (int k = tid; k < 512; k += 256) sK[k] = x[k];
        __syncthreads();
        const float* xq = sK + ks * 32;
        float acc = 0.f;
        #pragma unroll
        for (int k = 0; k < 32; ++k) acc += xq[k] * wreg[k];
        sp[tid] = acc;
        __syncthreads();
        if (tid < 16) {
            float a = ba[(blk - 144) * 16 + tid];
            #pragma unroll
            for (int u = 0; u < 16; ++u) a += sp[u * 16 + tid];
            ws[WS_ALPHA + (blk - 144) * 16 + tid] = 1.f / (1.f + __expf(-a));
        }
    } else {
        const int hl = tid & 15, ks = tid >> 4;        // 32 k each
        const int h = (blk - 176) * 16 + hl;           // 6*16 = 96
        const float* W = Wqr + (ks * 32) * 96 + h;
        float wreg[32];
        #pragma unroll
        for (int k = 0; k < 32; ++k) wreg[k] = W[k * 96];
        for (int k = tid; k < 512; k += 256) sK[k] = x[k];
        __syncthreads();
        const float* xq = sK + ks * 32;
        float acc = 0.f;
        #pragma unroll
        for (int k = 0; k < 32; ++k) acc += xq[k] * wreg[k];
        sp[tid] = acc;
        __syncthreads();
        if (tid < 16) {
            float a = bqr[(blk - 176) * 16 + tid];
            #pragma unroll
            for (int u = 0; u < 16; ++u) a += sp[u * 16 + tid];
            ws[WS_Q + (blk - 176) * 16 + tid] = fmaxf(a, 0.f);
        }
    }
}

// ---------------------------------------------------------------------------
// KBC v2 (64 x 256, STATIC ~25KB LDS): proc = blk%8 (XCD), e = blk/8.
// Each block redundantly computes attn1 -> fc1 (+Qq) -> K2/V2 -> attn2 ->
// fc2, then its 64-map Wo slice + epilogue. All weights from global
// (compile-time addressed, compiler-hoisted; 8-way L2-shared per XCD).
// ---------------------------------------------------------------------------
__global__ __launch_bounds__(256) void kBC_all(
    const float* __restrict__ gate, const float* __restrict__ De,
    const float* __restrict__ regs, const float* __restrict__ fc1w,
    const float* __restrict__ Wq2,  const float* __restrict__ Wk2,
    const float* __restrict__ Wv2,  const float* __restrict__ fc2w,
    const float* __restrict__ Wo,   const float* __restrict__ ws,
    float* __restrict__ out)
{
    const int b = blockIdx.x, proc = b & 7, e = b >> 3, tid = threadIdx.x;
    __shared__ float sQk[768], sKk[768], sVv[768], sH[768], sH2[768];
    __shared__ float sK2[768], sV2[768];
    __shared__ float sq[96], sQq[96], sO[96], sOf[96], sE2[128], sg[8];
    __shared__ float sS[192], sp[256];
    const float rs = 0.10206207261596577f;  // 1/sqrt(96)

    const float* qkv = ws + WS_QKV + proc * 2304;
    for (int i = tid; i < 768; i += 256) {
        sQk[i] = qkv[i]; sKk[i] = qkv[768 + i]; sVv[i] = qkv[1536 + i];
    }
    if (tid < 96) sq[tid] = ws[WS_Q + tid];
    else if (tid < 104) sg[tid - 96] = gate[tid - 96];
    // epilogue operands -> regs (duplicated across ks, cheap)
    const int ml = tid & 63, ks = tid >> 6;
    const int m = 64 * e + ml;
    const float4* Dp4 = (const float4*)(De + proc * 4096 + m * 8);
    const float4 d0 = Dp4[0], d1v = Dp4[1];
    const float av = ws[WS_ALPHA + m];
    const float rg = regs[proc * 512 + m];
    __syncthreads();

    // attn1 logits (h0, si, sk)
    if (tid < 192) {
        const int h0 = tid / 64, r64 = tid % 64, si = r64 / 8, sk = r64 % 8;
        float acc = 0.f;
        #pragma unroll
        for (int d = 0; d < 32; ++d)
            acc += sQk[si * 96 + h0 * 32 + d] * sKk[sk * 96 + h0 * 32 + d];
        sS[tid] = acc * rs;
    }
    __syncthreads();
    if (tid < 24) {        // softmax row -> probs in place
        float* row = sS + tid * 8;
        float mx = row[0];
        #pragma unroll
        for (int k = 1; k < 8; ++k) mx = fmaxf(mx, row[k]);
        float ex[8], sum = 0.f;
        #pragma unroll
        for (int k = 0; k < 8; ++k) { ex[k] = __expf(row[k] - mx); sum += ex[k]; }
        const float inv = 1.f / sum;
        #pragma unroll
        for (int k = 0; k < 8; ++k) row[k] = ex[k] * inv;
    }
    __syncthreads();
    if (tid < 192) {       // AV + residual (h0, si, dq): 4 d's each
        const int h0 = tid / 64, r64 = tid % 64, si = r64 / 8, dq = r64 % 8;
        const float* ep = sS + h0 * 64 + si * 8;
        float o0 = 0.f, o1 = 0.f, o2 = 0.f, o3 = 0.f;
        #pragma unroll
        for (int k = 0; k < 8; ++k) {
            const float ek = ep[k];
            const float* v = sVv + k * 96 + h0 * 32 + dq * 4;
            o0 += ek*v[0]; o1 += ek*v[1]; o2 += ek*v[2]; o3 += ek*v[3];
        }
        const int base = si * 96 + h0 * 32 + dq * 4;
        sH[base+0] = sQk[base+0] + o0;  sH[base+1] = sQk[base+1] + o1;
        sH[base+2] = sQk[base+2] + o2;  sH[base+3] = sQk[base+3] + o3;
    }
    __syncthreads();
    // fc1 from global: 3 outputs/thread; Qq from global (tid<96)
    #pragma unroll
    for (int r = 0; r < 3; ++r) {
        const int idx = tid + 256 * r, s = idx / 96, j = idx % 96;
        const float* W = fc1w + proc * 9216 + j;
        const float* Hs = sH + s * 96;
        float acc = 0.f;
        #pragma unroll
        for (int i = 0; i < 96; ++i) acc += Hs[i] * W[i * 96];
        sH2[idx] = sH[idx] + fmaxf(acc, 0.f);
    }
    if (tid < 96) {
        const float* W = Wq2 + proc * 9216 + tid;
        float acc = 0.f;
        #pragma unroll
        for (int i = 0; i < 96; ++i) acc += sq[i] * W[i * 96];
        sQq[tid] = acc;
    }
    __syncthreads();
    // K2/V2 from global: 6 outputs/thread
    #pragma unroll
    for (int r = 0; r < 6; ++r) {
        const int idx = tid + 256 * r;          // 0..1535
        const int mat = idx / 768, rr = idx % 768, s = rr / 96, j = rr % 96;
        const float* W = (mat ? Wv2 : Wk2) + proc * 9216 + j;
        const float* Hs = sH2 + s * 96;
        float acc = 0.f;
        #pragma unroll
        for (int i = 0; i < 96; ++i) acc += Hs[i] * W[i * 96];
        if (mat) sV2[rr] = acc; else sK2[rr] = acc;
    }
    __syncthreads();
    // attn2 probs: 16 heads, d=6, 1 query row
    if (tid < 16) {
        const int h0 = tid;
        float lg[8], mx = -1e30f;
        #pragma unroll
        for (int k = 0; k < 8; ++k) {
            float acc = 0.f;
            #pragma unroll
            for (int d = 0; d < 6; ++d)
                acc += sQq[h0 * 6 + d] * sK2[k * 96 + h0 * 6 + d];
            lg[k] = acc * rs; mx = fmaxf(mx, lg[k]);
        }
        float ex[8], sum = 0.f;
        #pragma unroll
        for (int k = 0; k < 8; ++k) { ex[k] = __expf(lg[k] - mx); sum += ex[k]; }
        const float inv = 1.f / sum;
        #pragma unroll
        for (int k = 0; k < 8; ++k) sE2[h0 * 8 + k] = ex[k] * inv;
    }
    __syncthreads();
    if (tid < 96) {        // AV + residual
        const int h0 = tid / 6;
        float o = 0.f;
        #pragma unroll
        for (int k = 0; k < 8; ++k) o += sE2[h0 * 8 + k] * sV2[k * 96 + tid];
        sO[tid] = sQq[tid] + o;
    }
    __syncthreads();
    if (tid < 96) {        // fc2 from global
        const float* W = fc2w + proc * 9216 + tid;
        float acc = 0.f;
        #pragma unroll
        for (int i = 0; i < 96; ++i) acc += sO[i] * W[i * 96];
        sOf[tid] = sO[tid] + fmaxf(acc, 0.f);
    }
    __syncthreads();
    // Wo slice from global (lanes contiguous m), 4-way k-split
    {
        const float* W = Wo + proc * 49152 + m;
        float acc = 0.f;
        #pragma unroll
        for (int i = 0; i < 24; ++i)
            acc += sOf[24 * ks + i] * W[(24 * ks + i) * 512];
        sp[tid] = acc;
    }
    __syncthreads();
    if (ks == 0) {
        const float tr = sp[ml] + sp[ml + 64] + sp[ml + 128] + sp[ml + 192];
        const float de = d0.x * sg[0] + d0.y * sg[1] + d0.z * sg[2] + d0.w * sg[3]
                       + d1v.x * sg[4] + d1v.y * sg[5] + d1v.z * sg[6] + d1v.w * sg[7];
        const float mix = av * tr + (1.f - av) * de;
        const int pt = proc & 3;                 // gamma gets +1, beta not
        const float off = (pt == 0 || pt == 2) ? 1.f : 0.f;
        out[proc * 512 + m] = mix * rg + off;
    }
}

extern "C" void kernel_launch(void* const* d_in, const int* in_sizes, int n_in,
                              void* d_out, int out_size, void* d_ws, size_t ws_size,
                              hipStream_t stream)
{
    const float* gate = (const float*)d_in[0];
    const float* x    = (const float*)d_in[1];
    const float* Wa   = (const float*)d_in[2];
    const float* ba   = (const float*)d_in[3];
    const float* Wqr  = (const float*)d_in[4];
    const float* bqr  = (const float*)d_in[5];
    const float* P    = (const float*)d_in[6];
    const float* De   = (const float*)d_in[7];
    const float* regs = (const float*)d_in[8];
    const float* Wq1  = (const float*)d_in[9];
    const float* Wk1  = (const float*)d_in[10];
    const float* Wv1  = (const float*)d_in[11];
    const float* fc1  = (const float*)d_in[12];
    const float* Wq2  = (const float*)d_in[13];
    const float* Wk2  = (const float*)d_in[14];
    const float* Wv2  = (const float*)d_in[15];
    const float* fc2  = (const float*)d_in[16];
    const float* Wo   = (const float*)d_in[17];
    float* ws = (float*)d_ws;

    hipLaunchKernelGGL(kA_qkv_alpha_q, dim3(182), dim3(256), 0, stream,
                       x, Wa, ba, Wqr, bqr, P, Wq1, Wk1, Wv1, ws);
    hipLaunchKernelGGL(kBC_all, dim3(64), dim3(256), 0, stream,
                       gate, De, regs, fc1, Wq2, Wk2, Wv2, fc2, Wo,
                       ws, (float*)d_out);
}

// Round 13
// 107.240 us; speedup vs baseline: 1.0758x; 1.0299x over previous
//
#include <hip/hip_runtime.h>
#include <hip/hip_bf16.h>
#include <math.h>

// NUM_MAPS=512, ZG=512, HID=96, SEQ=8, H1=3, H2=16, NPROC=8. fp32 in/out.
// R12 post-mortem: static-LDS kBC killed the >64KB-dynamic-LDS ~50us
// dispatch tax (54.5 -> ~7us, confirming R11 hypothesis) but the 2-kernel
// merge is still 110.45 vs R10's 107.9: per-block redundant serial chain
// (full fc1 + full K2/V2) costs ~5us > the ~2.5us launch gap it saves.
// Kernel-count bracket: {1:138(tax), 2:110.5, 3:107.9*, 6:115.9, 7:116.6}.
// R13: exact revert to R10 (verified session best, 107.9us).

#define WS_ALPHA 0
#define WS_Q     512
#define WS_QKV   608      // 8*2304 -> 19040
#define WS_K2    19040    // 8*768  -> 25184
#define WS_V2    25184    // 8*768  -> 31328
#define WS_QQ    31328    // 8*96   -> 32096

// ---------------------------------------------------------------------------
// KA (182 x 256):
//  blk 0..143   : QKV1. proc = blk%8 (XCD), rem = blk/8 -> (mat, six).
//  blk 144..175 : alpha. 16 m/blk, 16-way k-split, W hoisted.
//  blk 176..181 : q. 16 h/blk, 16-way k-split, W hoisted.
// ---------------------------------------------------------------------------
__global__ __launch_bounds__(256) void kA_qkv_alpha_q(
    const float* __restrict__ x, const float* __restrict__ Wa,
    const float* __restrict__ ba, const float* __restrict__ Wqr,
    const float* __restrict__ bqr, const float* __restrict__ P,
    const float* __restrict__ Wq1, const float* __restrict__ Wk1,
    const float* __restrict__ Wv1, float* __restrict__ ws)
{
    __shared__ float sK[8 * 528];   // skewed K tile (c -> c + c/32), or x
    __shared__ float sp[2048];      // partial sums
    const int blk = blockIdx.x, tid = threadIdx.x;

    if (blk < 144) {
        const int proc = blk & 7, rem = blk >> 3;       // proc -> XCD
        const int mat = rem / 6, six = rem % 6;
        const int hl = tid & 15, ks = tid >> 4;        // ks 0..15
        const int h = six * 16 + hl;
        const float* W = (mat == 0 ? Wq1 : (mat == 1 ? Wk1 : Wv1))
                         + proc * 49152 + (ks * 32) * 96 + h;
        float wreg[32];
        #pragma unroll
        for (int m2 = 0; m2 < 32; ++m2) wreg[m2] = W[m2 * 96];  // issued early
        const float4* P4 = (const float4*)(P + proc * 4096);
        for (int i = tid; i < 1024; i += 256) {
            float4 v = P4[i];
            const int c = i >> 1, off = (i & 1) * 4;
            const int cp = c + (c >> 5);
            sK[(off + 0) * 528 + cp] = v.x;
            sK[(off + 1) * 528 + cp] = v.y;
            sK[(off + 2) * 528 + cp] = v.z;
            sK[(off + 3) * 528 + cp] = v.w;
        }
        __syncthreads();
        const float* Kb = sK + ks * 33;                // skewed base
        float acc[8] = {0.f,0.f,0.f,0.f,0.f,0.f,0.f,0.f};
        #pragma unroll
        for (int m2 = 0; m2 < 32; ++m2) {
            const float w = wreg[m2];
            const float* Kc = Kb + m2;
            #pragma unroll
            for (int s = 0; s < 8; ++s) acc[s] += Kc[s * 528] * w;
        }
        float* spb = sp + ks * 128 + hl * 8;
        #pragma unroll
        for (int s = 0; s < 8; ++s) spb[s] = acc[s];
        __syncthreads();
        if (tid < 128) {            // tid = hl2*8 + s
            float a = 0.f;
            #pragma unroll
            for (int u = 0; u < 16; ++u) a += sp[u * 128 + tid];
            const int hl2 = tid >> 3, s = tid & 7;
            ws[WS_QKV + proc * 2304 + mat * 768 + s * 96 + six * 16 + hl2] = a;
        }
    } else if (blk < 176) {
        const int ml = tid & 15, ks = tid >> 4;        // 32 k each
        const int m = (blk - 144) * 16 + ml;
        const float* W = Wa + (ks * 32) * 512 + m;
        float wreg[32];
        #pragma unroll
        for (int k = 0; k < 32; ++k) wreg[k] = W[k * 512];
        for (int k = tid; k < 512; k += 256) sK[k] = x[k];
        __syncthreads();
        const float* xq = sK + ks * 32;
        float acc = 0.f;
        #pragma unroll
        for (int k = 0; k < 32; ++k) acc += xq[k] * wreg[k];
        sp[tid] = acc;
        __syncthreads();
        if (tid < 16) {
            float a = ba[(blk - 144) * 16 + tid];
            #pragma unroll
            for (int u = 0; u < 16; ++u) a += sp[u * 16 + tid];
            ws[WS_ALPHA + (blk - 144) * 16 + tid] = 1.f / (1.f + __expf(-a));
        }
    } else {
        const int hl = tid & 15, ks = tid >> 4;        // 32 k each
        const int h = (blk - 176) * 16 + hl;           // 6*16 = 96
        const float* W = Wqr + (ks * 32) * 96 + h;
        float wreg[32];
        #pragma unroll
        for (int k = 0; k < 32; ++k) wreg[k] = W[k * 96];
        for (int k = tid; k < 512; k += 256) sK[k] = x[k];
        __syncthreads();
        const float* xq = sK + ks * 32;
        float acc = 0.f;
        #pragma unroll
        for (int k = 0; k < 32; ++k) acc += xq[k] * wreg[k];
        sp[tid] = acc;
        __syncthreads();
        if (tid < 16) {
            float a = bqr[(blk - 176) * 16 + tid];
            #pragma unroll
            for (int u = 0; u < 16; ++u) a += sp[u * 16 + tid];
            ws[WS_Q + (blk - 176) * 16 + tid] = fmaxf(a, 0.f);
        }
    }
}

// ---------------------------------------------------------------------------
// KB (72 x 256): blk<48: proc = blk%8 (XCD), slot = blk/8 -> (mat, t).
// Entry burst-stages fc1 (36KB, 6x L2-shared) + Wk2/Wv2 slice (12KB) into
// LDS, then attn1 -> fc1 -> K2/V2 slice.
// blk 48..71: Qq = q @ Wq2; proc = (blk-48)%8, t = (blk-48)/8.
// ---------------------------------------------------------------------------
__global__ __launch_bounds__(256) void kB_attn1_fc1_kv2(
    const float* __restrict__ fc1w, const float* __restrict__ Wk2,
    const float* __restrict__ Wv2, const float* __restrict__ Wq2,
    float* __restrict__ ws)
{
    const int b = blockIdx.x, tid = threadIdx.x;
    const float rs = 0.10206207261596577f;  // 1/sqrt(96)

    if (b < 48) {
        const int proc = b & 7, slot = b >> 3;          // proc -> XCD
        const int mat = slot / 3, t = slot % 3;
        __shared__ float sQk[768], sKk[768], sVv[768], sH[768], sH2[768], sS[192];
        __shared__ float sWf1[9216];     // fc1, row-major [i][j]
        __shared__ float sWkv[96 * 32];  // Wk2/Wv2 column slice [i][jl]

        // ---- entry burst: all weight bytes, coalesced float4, once ----
        {
            const float4* F4 = (const float4*)fc1w + proc * 2304;
            float4* D4 = (float4*)sWf1;
            #pragma unroll
            for (int r = 0; r < 9; ++r) D4[tid + 256 * r] = F4[tid + 256 * r];
            const float4* KV4 = (const float4*)(mat ? Wv2 : Wk2);
            float4* E4 = (float4*)sWkv;
            #pragma unroll
            for (int r = 0; r < 3; ++r) {
                const int idx = tid + 256 * r;          // 768 float4
                const int row = idx >> 3, q4 = idx & 7;
                E4[row * 8 + q4] = KV4[proc * 2304 + row * 24 + t * 8 + q4];
            }
        }
        const float* qkv = ws + WS_QKV + proc * 2304;
        for (int i = tid; i < 768; i += 256) {
            sQk[i] = qkv[i]; sKk[i] = qkv[768 + i]; sVv[i] = qkv[1536 + i];
        }
        __syncthreads();

        if (tid < 192) {       // attn1 logits (h0, si, sk)
            const int h0 = tid / 64, r64 = tid % 64, si = r64 / 8, sk = r64 % 8;
            float acc = 0.f;
            #pragma unroll
            for (int d = 0; d < 32; ++d)
                acc += sQk[si * 96 + h0 * 32 + d] * sKk[sk * 96 + h0 * 32 + d];
            sS[tid] = acc * rs;
        }
        __syncthreads();
        if (tid < 24) {        // softmax row -> probs in place
            float* row = sS + tid * 8;
            float mx = row[0];
            #pragma unroll
            for (int k = 1; k < 8; ++k) mx = fmaxf(mx, row[k]);
            float e[8], sum = 0.f;
            #pragma unroll
            for (int k = 0; k < 8; ++k) { e[k] = __expf(row[k] - mx); sum += e[k]; }
            const float inv = 1.f / sum;
            #pragma unroll
            for (int k = 0; k < 8; ++k) row[k] = e[k] * inv;
        }
        __syncthreads();
        if (tid < 192) {       // AV + residual (h0, si, dq): 4 d's each
            const int h0 = tid / 64, r64 = tid % 64, si = r64 / 8, dq = r64 % 8;
            const float* e = sS + h0 * 64 + si * 8;
            float o0 = 0.f, o1 = 0.f, o2 = 0.f, o3 = 0.f;
            #pragma unroll
            for (int k = 0; k < 8; ++k) {
                const float ek = e[k];
                const float* v = sVv + k * 96 + h0 * 32 + dq * 4;
                o0 += ek*v[0]; o1 += ek*v[1]; o2 += ek*v[2]; o3 += ek*v[3];
            }
            const int base = si * 96 + h0 * 32 + dq * 4;
            sH[base+0] = sQk[base+0] + o0;  sH[base+1] = sQk[base+1] + o1;
            sH[base+2] = sQk[base+2] + o2;  sH[base+3] = sQk[base+3] + o3;
        }
        __syncthreads();
        // fc1 from LDS (full, redundant): 3 outputs/thread
        #pragma unroll
        for (int r = 0; r < 3; ++r) {
            const int idx = tid + 256 * r, s = idx / 96, j = idx % 96;
            const float* Hs = sH + s * 96;
            float acc = 0.f;
            #pragma unroll
            for (int i = 0; i < 96; ++i) acc += Hs[i] * sWf1[i * 96 + j];
            sH2[idx] = sH[idx] + fmaxf(acc, 0.f);
        }
        __syncthreads();
        // K2/V2 slice from LDS: (s, jl)
        const int s = tid >> 5, jl = tid & 31, j = t * 32 + jl;
        const float* Hs = sH2 + s * 96;
        float acc = 0.f;
        #pragma unroll
        for (int i = 0; i < 96; ++i) acc += Hs[i] * sWkv[i * 32 + jl];
        ws[(mat ? WS_V2 : WS_K2) + proc * 768 + s * 96 + j] = acc;
    } else {
        const int b2 = b - 48, proc = b2 & 7, t = b2 >> 3;   // proc -> XCD
        __shared__ float sq[96], sp[256];
        if (tid < 96) sq[tid] = ws[WS_Q + tid];
        __syncthreads();
        const int jl = tid & 31, ks = tid >> 5;
        const int j = 32 * t + jl;
        const float* W = Wq2 + proc * 9216 + j;
        float acc = 0.f;
        #pragma unroll
        for (int i = 0; i < 12; ++i)
            acc += sq[12 * ks + i] * W[(12 * ks + i) * 96];
        sp[tid] = acc;
        __syncthreads();
        if (ks == 0) {
            float a = 0.f;
            #pragma unroll
            for (int u = 0; u < 8; ++u) a += sp[jl + 32 * u];
            ws[WS_QQ + proc * 96 + j] = a;
        }
    }
}

// ---------------------------------------------------------------------------
// KC (64 x 256): proc = blk%8 (XCD), e = blk/8. Entry burst-stages fc2
// (36KB, 8x L2-shared) + Wo slice (24KB) into LDS + K2/V2/Qq from ws +
// De/alpha/regs into regs. Then attn2, fc2, Wo slice + epilogue.
// ---------------------------------------------------------------------------
__global__ __launch_bounds__(256) void kC_attn2_fc2_out(
    const float* __restrict__ gate, const float* __restrict__ De,
    const float* __restrict__ regs, const float* __restrict__ fc2w,
    const float* __restrict__ Wo, const float* __restrict__ ws,
    float* __restrict__ out)
{
    const int b = blockIdx.x, proc = b & 7, e = b >> 3, tid = threadIdx.x;
    __shared__ float sK2[768], sV2[768];
    __shared__ float sQq[96], sO[96], sOf[96], sE2[128], sg[8], sp[256];
    __shared__ float sWf2[9216];     // fc2 [i][j]
    __shared__ float sWo[96 * 64];   // Wo slice [h][ml]
    const float rs = 0.10206207261596577f;

    // ---- entry burst ----
    {
        const float4* F4 = (const float4*)fc2w + proc * 2304;
        float4* D4 = (float4*)sWf2;
        #pragma unroll
        for (int r = 0; r < 9; ++r) D4[tid + 256 * r] = F4[tid + 256 * r];
        const float4* W4 = (const float4*)Wo;
        float4* E4 = (float4*)sWo;
        #pragma unroll
        for (int r = 0; r < 6; ++r) {
            const int idx = tid + 256 * r;              // 1536 float4
            const int row = idx >> 4, q4 = idx & 15;
            E4[row * 16 + q4] = W4[proc * 12288 + row * 128 + e * 16 + q4];
        }
    }
    const int ml = tid & 63, ks = tid >> 6;
    const int m = 64 * e + ml;
    // epilogue operands prefetched into regs (redundant across ks, cheap)
    const float4* Dp4 = (const float4*)(De + proc * 4096 + m * 8);
    const float4 d0 = Dp4[0], d1 = Dp4[1];
    const float av = ws[WS_ALPHA + m];
    const float rg = regs[proc * 512 + m];
    for (int i = tid; i < 768; i += 256) {
        sK2[i] = ws[WS_K2 + proc * 768 + i];
        sV2[i] = ws[WS_V2 + proc * 768 + i];
    }
    if (tid < 96) sQq[tid] = ws[WS_QQ + proc * 96 + tid];
    else if (tid >= 96 && tid < 104) sg[tid - 96] = gate[tid - 96];
    __syncthreads();

    // attn2 probs: 16 heads, d=6, 1 query row
    if (tid < 16) {
        const int h0 = tid;
        float lg[8], mx = -1e30f;
        #pragma unroll
        for (int k = 0; k < 8; ++k) {
            float acc = 0.f;
            #pragma unroll
            for (int d = 0; d < 6; ++d)
                acc += sQq[h0 * 6 + d] * sK2[k * 96 + h0 * 6 + d];
            lg[k] = acc * rs; mx = fmaxf(mx, lg[k]);
        }
        float ex[8], sum = 0.f;
        #pragma unroll
        for (int k = 0; k < 8; ++k) { ex[k] = __expf(lg[k] - mx); sum += ex[k]; }
        const float inv = 1.f / sum;
        #pragma unroll
        for (int k = 0; k < 8; ++k) sE2[h0 * 8 + k] = ex[k] * inv;
    }
    __syncthreads();
    if (tid < 96) {           // AV + residual
        const int h0 = tid / 6;
        float o = 0.f;
        #pragma unroll
        for (int k = 0; k < 8; ++k) o += sE2[h0 * 8 + k] * sV2[k * 96 + tid];
        sO[tid] = sQq[tid] + o;
    }
    __syncthreads();
    if (tid < 192) {          // fc2 from LDS, 2-way k-split
        const int j = tid % 96, k2 = tid / 96;
        const float* Os = sO + k2 * 48;
        float acc = 0.f;
        #pragma unroll
        for (int i = 0; i < 48; ++i) acc += Os[i] * sWf2[(k2 * 48 + i) * 96 + j];
        sp[tid] = acc;
    }
    __syncthreads();
    if (tid < 96) sOf[tid] = sO[tid] + fmaxf(sp[tid] + sp[96 + tid], 0.f);
    __syncthreads();

    // Wo slice from LDS: 64 maps, 4-way k-split
    float acc = 0.f;
    #pragma unroll
    for (int i = 0; i < 24; ++i)
        acc += sOf[24 * ks + i] * sWo[(24 * ks + i) * 64 + ml];
    sp[tid] = acc;
    __syncthreads();
    if (ks == 0) {
        const float tr = sp[ml] + sp[ml + 64] + sp[ml + 128] + sp[ml + 192];
        const float de = d0.x * sg[0] + d0.y * sg[1] + d0.z * sg[2] + d0.w * sg[3]
                       + d1.x * sg[4] + d1.y * sg[5] + d1.z * sg[6] + d1.w * sg[7];
        const float mix = av * tr + (1.f - av) * de;
        const int pt = proc & 3;                 // gamma gets +1, beta not
        const float off = (pt == 0 || pt == 2) ? 1.f : 0.f;
        out[proc * 512 + m] = mix * rg + off;
    }
}

extern "C" void kernel_launch(void* const* d_in, const int* in_sizes, int n_in,
                              void* d_out, int out_size, void* d_ws, size_t ws_size,
                              hipStream_t stream)
{
    const float* gate = (const float*)d_in[0];
    const float* x    = (const float*)d_in[1];
    const float* Wa   = (const float*)d_in[2];
    const float* ba   = (const float*)d_in[3];
    const float* Wqr  = (const float*)d_in[4];
    const float* bqr  = (const float*)d_in[5];
    const float* P    = (const float*)d_in[6];
    const float* De   = (const float*)d_in[7];
    const float* regs = (const float*)d_in[8];
    const float* Wq1  = (const float*)d_in[9];
    const float* Wk1  = (const float*)d_in[10];
    const float* Wv1  = (const float*)d_in[11];
    const float* fc1  = (const float*)d_in[12];
    const float* Wq2  = (const float*)d_in[13];
    const float* Wk2  = (const float*)d_in[14];
    const float* Wv2  = (const float*)d_in[15];
    const float* fc2  = (const float*)d_in[16];
    const float* Wo   = (const float*)d_in[17];
    float* ws = (float*)d_ws;

    hipLaunchKernelGGL(kA_qkv_alpha_q, dim3(182), dim3(256), 0, stream,
                       x, Wa, ba, Wqr, bqr, P, Wq1, Wk1, Wv1, ws);
    hipLaunchKernelGGL(kB_attn1_fc1_kv2, dim3(72), dim3(256), 0, stream,
                       fc1, Wk2, Wv2, Wq2, ws);
    hipLaunchKernelGGL(kC_attn2_fc2_out, dim3(64), dim3(256), 0, stream,
                       gate, De, regs, fc2, Wo, ws, (float*)d_out);
}